// Round 1
// baseline (414.700 us; speedup 1.0000x reference)
//
#include <hip/hip_runtime.h>
#include <stdint.h>

#define N_TOK 8192
#define DIMD 1024
#define NEXP 8
#define HDIM 2048
#define BM 128
#define BN 128
#define BKK 64
#define MAXTILES 136            // sum ceil(c_e/128) <= 16384/128 + 8
#define MAXROWS (MAXTILES * BM) // 17408 padded row slots

typedef __attribute__((ext_vector_type(8))) short short8;
typedef __attribute__((ext_vector_type(4))) float f32x4;

__device__ __forceinline__ ushort f2bf(float f) {
    uint32_t u = __float_as_uint(f);
    u += 0x7fffu + ((u >> 16) & 1u);   // round-to-nearest-even
    return (ushort)(u >> 16);
}

// global -> LDS direct staging, 16B per lane. LDS dest must be wave-uniform.
// uintptr_t route for addrspace casts (CK-style): generic LDS ptr low 32 bits
// are the LDS offset; global flat address == AS1 address.
__device__ __forceinline__ void gload_lds16(const void* gsrc, void* lds_dst) {
    __builtin_amdgcn_global_load_lds(
        (const __attribute__((address_space(1))) void*)(uintptr_t)(gsrc),
        (__attribute__((address_space(3))) void*)(uintptr_t)(lds_dst),
        16, 0, 0);
}

// ---------------- conversion kernels ----------------

__global__ void conv_x_kernel(const float* __restrict__ x, ushort* __restrict__ xb) {
    int i = blockIdx.x * blockDim.x + threadIdx.x;  // 1M threads, 8 floats each
    int base = i * 8;
    const float4* p = (const float4*)(x + base);
    float4 a = p[0], b = p[1];
    alignas(16) ushort tmp[8];
    tmp[0] = f2bf(a.x); tmp[1] = f2bf(a.y); tmp[2] = f2bf(a.z); tmp[3] = f2bf(a.w);
    tmp[4] = f2bf(b.x); tmp[5] = f2bf(b.y); tmp[6] = f2bf(b.z); tmp[7] = f2bf(b.w);
    *(short8*)(xb + base) = *(const short8*)tmp;
}

// in: [E][R][C] f32 -> out: [E][C][R] bf16  (transpose so K becomes contiguous)
__global__ void transpose_cvt(const float* __restrict__ in, ushort* __restrict__ out,
                              int R, int C) {
    __shared__ float t[32][33];
    int e = blockIdx.x, r0 = blockIdx.y * 32, c0 = blockIdx.z * 32;
    const float* pin = in + (size_t)e * R * C;
    ushort* pout = out + (size_t)e * R * C;
    int c = threadIdx.x & 31, g = threadIdx.x >> 5;  // g in 0..7
#pragma unroll
    for (int i = 0; i < 4; i++) {
        int r = g + i * 8;
        t[r][c] = pin[(size_t)(r0 + r) * C + c0 + c];
    }
    __syncthreads();
#pragma unroll
    for (int i = 0; i < 4; i++) {
        int cc = g + i * 8;
        pout[(size_t)(c0 + cc) * R + r0 + c] = f2bf(t[c][cc]);
    }
}

// ---------------- gate ----------------

__global__ void gate_kernel(const float* __restrict__ x, const float* __restrict__ gw,
                            const float* __restrict__ gb, int* __restrict__ topi,
                            float* __restrict__ topw, int* __restrict__ counts,
                            float* __restrict__ probsum) {
    __shared__ float ps[NEXP];
    __shared__ int cs[NEXP];
    int tid = threadIdx.x;
    if (tid < NEXP) { ps[tid] = 0.f; cs[tid] = 0; }
    __syncthreads();
    int wid = tid >> 6, lane = tid & 63;
    int n = blockIdx.x * 4 + wid;          // one wave per token
    const float* xr = x + (size_t)n * DIMD;
    float acc[NEXP];
#pragma unroll
    for (int e = 0; e < NEXP; e++) acc[e] = 0.f;
    for (int i = 0; i < DIMD / 64; i++) {
        int c = lane + i * 64;
        float xv = xr[c];
        const float* g = gw + (size_t)c * NEXP;
#pragma unroll
        for (int e = 0; e < NEXP; e++) acc[e] += xv * g[e];
    }
#pragma unroll
    for (int e = 0; e < NEXP; e++) {
        float v = acc[e];
#pragma unroll
        for (int off = 32; off > 0; off >>= 1) v += __shfl_xor(v, off);
        acc[e] = v + gb[e];
    }
    float m = acc[0];
#pragma unroll
    for (int e = 1; e < NEXP; e++) m = fmaxf(m, acc[e]);
    float p[NEXP], s = 0.f;
#pragma unroll
    for (int e = 0; e < NEXP; e++) { p[e] = expf(acc[e] - m); s += p[e]; }
    int e1 = 0;
#pragma unroll
    for (int e = 1; e < NEXP; e++) if (p[e] > p[e1]) e1 = e;
    int e2 = (e1 == 0) ? 1 : 0;
#pragma unroll
    for (int e = 0; e < NEXP; e++) if (e != e1 && p[e] > p[e2]) e2 = e;
    float wa = p[e1] / (p[e1] + p[e2]);
    if (lane == 0) {
        topi[n * 2] = e1; topi[n * 2 + 1] = e2;
        topw[n * 2] = wa; topw[n * 2 + 1] = 1.f - wa;
        atomicAdd(&cs[e1], 1); atomicAdd(&cs[e2], 1);
        float inv = 1.f / s;
#pragma unroll
        for (int e = 0; e < NEXP; e++) atomicAdd(&ps[e], p[e] * inv);
    }
    __syncthreads();
    if (tid < NEXP) { atomicAdd(&probsum[tid], ps[tid]); atomicAdd(&counts[tid], cs[tid]); }
}

// ---------------- routing ----------------

__global__ void plan_kernel(const int* __restrict__ counts, int* __restrict__ pbase,
                            int2* __restrict__ tiles, int* __restrict__ ntiles) {
    if (threadIdx.x != 0) return;
    int slot = 0, t = 0;
    for (int e = 0; e < NEXP; e++) {
        pbase[e] = slot;
        int nt = (counts[e] + BM - 1) / BM;
        for (int i = 0; i < nt; i++) { tiles[t] = make_int2(e, slot + i * BM); t++; }
        slot += nt * BM;
    }
    *ntiles = t;
}

__global__ void init_rows_kernel(int* __restrict__ row_token, float* __restrict__ row_weight) {
    int i = blockIdx.x * blockDim.x + threadIdx.x;
    if (i < MAXROWS) { row_token[i] = 0; row_weight[i] = 0.f; }  // padding: token0, weight0
}

__global__ void scatter_kernel(const int* __restrict__ topi, const float* __restrict__ topw,
                               const int* __restrict__ pbase, int* __restrict__ cursor,
                               int* __restrict__ row_token, float* __restrict__ row_weight) {
    __shared__ int lcnt[NEXP], lbase[NEXP];
    int t = blockIdx.x * 256 + threadIdx.x;       // pair index
    if (threadIdx.x < NEXP) lcnt[threadIdx.x] = 0;
    __syncthreads();
    int e = topi[t];
    int lpos = atomicAdd(&lcnt[e], 1);
    __syncthreads();
    if (threadIdx.x < NEXP) lbase[threadIdx.x] = atomicAdd(&cursor[threadIdx.x], lcnt[threadIdx.x]);
    __syncthreads();
    int pos = pbase[e] + lbase[e] + lpos;
    row_token[pos] = t >> 1;
    row_weight[pos] = topw[t];
}

// ---------------- grouped GEMMs ----------------
// 128x128 tile, BK=64, 4 waves (2x2), mfma_f32_16x16x32_bf16.
// LDS XOR-swizzle (byte ^= (row&7)<<4) applied on BOTH staging source and read.

__global__ void gemm1_kernel(const ushort* __restrict__ xb, const ushort* __restrict__ w1t,
                             const float* __restrict__ b1, ushort* __restrict__ hbuf,
                             const int* __restrict__ row_token, const int2* __restrict__ tiles,
                             const int* __restrict__ ntiles) {
    int tm = blockIdx.x;
    if (tm >= *ntiles) return;
    int e = tiles[tm].x;
    int slotbase = tiles[tm].y;
    int nbase = blockIdx.y * BN;
    __shared__ alignas(16) ushort ldsA[BM * BKK];
    __shared__ alignas(16) ushort ldsB[BN * BKK];
    int tid = threadIdx.x, lane = tid & 63, wid = tid >> 6;
    int wr = wid >> 1, wc = wid & 1;
    f32x4 acc[4][4];
#pragma unroll
    for (int i = 0; i < 4; i++)
#pragma unroll
        for (int j = 0; j < 4; j++) acc[i][j] = (f32x4){0.f, 0.f, 0.f, 0.f};
    int arow[4], acol[4], tok[4];
#pragma unroll
    for (int i = 0; i < 4; i++) {
        int p = i * 4096 + wid * 1024 + lane * 16;   // linear LDS byte offset
        int row = p >> 7;
        int srclo = (p & 127) ^ ((row & 7) << 4);    // inverse-swizzled source column
        arow[i] = row; acol[i] = srclo >> 1;
        tok[i] = row_token[slotbase + row];
    }
    const ushort* bmat = w1t + (size_t)e * HDIM * DIMD;
    for (int kt = 0; kt < DIMD / BKK; kt++) {
        int k0 = kt * BKK;
#pragma unroll
        for (int i = 0; i < 4; i++) {
            gload_lds16(xb + (size_t)tok[i] * DIMD + k0 + acol[i], ldsA + i * 2048 + wid * 512);
            gload_lds16(bmat + (size_t)(nbase + arow[i]) * DIMD + k0 + acol[i],
                        ldsB + i * 2048 + wid * 512);
        }
        __syncthreads();
#pragma unroll
        for (int kk = 0; kk < 2; kk++) {
            short8 af[4], bfv[4];
#pragma unroll
            for (int im = 0; im < 4; im++) {
                int row = wr * 64 + im * 16 + (lane & 15);
                int kbyte = kk * 64 + ((lane >> 4) * 16);
                int off = row * 128 + (kbyte ^ ((row & 7) << 4));
                af[im] = *(const short8*)((const char*)ldsA + off);
            }
#pragma unroll
            for (int in = 0; in < 4; in++) {
                int row = wc * 64 + in * 16 + (lane & 15);
                int kbyte = kk * 64 + ((lane >> 4) * 16);
                int off = row * 128 + (kbyte ^ ((row & 7) << 4));
                bfv[in] = *(const short8*)((const char*)ldsB + off);
            }
#pragma unroll
            for (int im = 0; im < 4; im++)
#pragma unroll
                for (int in = 0; in < 4; in++)
                    acc[im][in] = __builtin_amdgcn_mfma_f32_16x16x32_bf16(af[im], bfv[in],
                                                                          acc[im][in], 0, 0, 0);
        }
        __syncthreads();
    }
    const float* b1e = b1 + (size_t)e * HDIM;
#pragma unroll
    for (int im = 0; im < 4; im++) {
#pragma unroll
        for (int in = 0; in < 4; in++) {
            int col = nbase + wc * 64 + in * 16 + (lane & 15);
            float bias = b1e[col];
#pragma unroll
            for (int r = 0; r < 4; r++) {
                int row = slotbase + wr * 64 + im * 16 + (lane >> 4) * 4 + r;
                float v = fmaxf(acc[im][in][r] + bias, 0.f);
                hbuf[(size_t)row * HDIM + col] = f2bf(v);
            }
        }
    }
}

__global__ void gemm2_kernel(const ushort* __restrict__ hbuf, const ushort* __restrict__ w2t,
                             const float* __restrict__ b2, float* __restrict__ outp,
                             const int* __restrict__ row_token, const float* __restrict__ row_weight,
                             const int2* __restrict__ tiles, const int* __restrict__ ntiles) {
    int tm = blockIdx.x;
    if (tm >= *ntiles) return;
    int e = tiles[tm].x;
    int slotbase = tiles[tm].y;
    int nbase = blockIdx.y * BN;
    __shared__ alignas(16) ushort ldsA[BM * BKK];
    __shared__ alignas(16) ushort ldsB[BN * BKK];
    int tid = threadIdx.x, lane = tid & 63, wid = tid >> 6;
    int wr = wid >> 1, wc = wid & 1;
    f32x4 acc[4][4];
#pragma unroll
    for (int i = 0; i < 4; i++)
#pragma unroll
        for (int j = 0; j < 4; j++) acc[i][j] = (f32x4){0.f, 0.f, 0.f, 0.f};
    int arow[4], acol[4];
#pragma unroll
    for (int i = 0; i < 4; i++) {
        int p = i * 4096 + wid * 1024 + lane * 16;
        int row = p >> 7;
        int srclo = (p & 127) ^ ((row & 7) << 4);
        arow[i] = row; acol[i] = srclo >> 1;
    }
    const ushort* bmat = w2t + (size_t)e * DIMD * HDIM;
    for (int kt = 0; kt < HDIM / BKK; kt++) {
        int k0 = kt * BKK;
#pragma unroll
        for (int i = 0; i < 4; i++) {
            gload_lds16(hbuf + (size_t)(slotbase + arow[i]) * HDIM + k0 + acol[i],
                        ldsA + i * 2048 + wid * 512);
            gload_lds16(bmat + (size_t)(nbase + arow[i]) * HDIM + k0 + acol[i],
                        ldsB + i * 2048 + wid * 512);
        }
        __syncthreads();
#pragma unroll
        for (int kk = 0; kk < 2; kk++) {
            short8 af[4], bfv[4];
#pragma unroll
            for (int im = 0; im < 4; im++) {
                int row = wr * 64 + im * 16 + (lane & 15);
                int kbyte = kk * 64 + ((lane >> 4) * 16);
                int off = row * 128 + (kbyte ^ ((row & 7) << 4));
                af[im] = *(const short8*)((const char*)ldsA + off);
            }
#pragma unroll
            for (int in = 0; in < 4; in++) {
                int row = wc * 64 + in * 16 + (lane & 15);
                int kbyte = kk * 64 + ((lane >> 4) * 16);
                int off = row * 128 + (kbyte ^ ((row & 7) << 4));
                bfv[in] = *(const short8*)((const char*)ldsB + off);
            }
#pragma unroll
            for (int im = 0; im < 4; im++)
#pragma unroll
                for (int in = 0; in < 4; in++)
                    acc[im][in] = __builtin_amdgcn_mfma_f32_16x16x32_bf16(af[im], bfv[in],
                                                                          acc[im][in], 0, 0, 0);
        }
        __syncthreads();
    }
    const float* b2e = b2 + (size_t)e * DIMD;
#pragma unroll
    for (int im = 0; im < 4; im++) {
#pragma unroll
        for (int r = 0; r < 4; r++) {
            int srow = slotbase + wr * 64 + im * 16 + (lane >> 4) * 4 + r;
            int token = row_token[srow];
            float w = row_weight[srow];
            float* orow = outp + (size_t)token * DIMD;
#pragma unroll
            for (int in = 0; in < 4; in++) {
                int col = nbase + wc * 64 + in * 16 + (lane & 15);
                float v = acc[im][in][r] + b2e[col];
                atomicAdd(&orow[col], w * v);
            }
        }
    }
}

__global__ void finalize_kernel(const float* __restrict__ probsum, const int* __restrict__ counts,
                                float* __restrict__ loss_out) {
    if (threadIdx.x == 0) {
        float l = 0.f;
        for (int e = 0; e < NEXP; e++) l += probsum[e] * (float)counts[e];
        *loss_out = l / ((float)N_TOK * (float)N_TOK);
    }
}

// ---------------- launch ----------------

extern "C" void kernel_launch(void* const* d_in, const int* in_sizes, int n_in,
                              void* d_out, int out_size, void* d_ws, size_t ws_size,
                              hipStream_t stream) {
    const float* x      = (const float*)d_in[0];
    const float* gate_w = (const float*)d_in[1];
    const float* gate_b = (const float*)d_in[2];
    const float* w1     = (const float*)d_in[3];
    const float* b1     = (const float*)d_in[4];
    const float* w2     = (const float*)d_in[5];
    const float* b2     = (const float*)d_in[6];
    float* outp = (float*)d_out;

    char* ws = (char*)d_ws;
    ushort* xb   = (ushort*)(ws);                 // 16 MB
    ushort* w1t  = (ushort*)(ws + 16777216);      // 32 MB  [E][H][D] bf16
    ushort* w2t  = (ushort*)(ws + 50331648);      // 32 MB  [E][D][H] bf16
    ushort* hbuf = (ushort*)(ws + 83886080);      // 68 MB  [MAXROWS][H] bf16
    char* ctrl   = ws + 155189248;
    int*   counts     = (int*)(ctrl + 0);
    int*   cursor     = (int*)(ctrl + 32);
    float* probsum    = (float*)(ctrl + 64);
    int*   ntiles     = (int*)(ctrl + 96);
    int*   pbase      = (int*)(ctrl + 128);
    int2*  tiles      = (int2*)(ctrl + 160);
    int*   topi       = (int*)(ctrl + 2048);
    float* topw       = (float*)(ctrl + 2048 + 65536);
    int*   row_token  = (int*)(ctrl + 2048 + 131072);
    float* row_weight = (float*)(ctrl + 2048 + 131072 + 69632);

    hipMemsetAsync(ctrl, 0, 128, stream);                                  // counts/cursor/probsum/ntiles
    hipMemsetAsync(d_out, 0, (size_t)out_size * sizeof(float), stream);    // final accumulated via atomics

    conv_x_kernel<<<4096, 256, 0, stream>>>(x, xb);
    transpose_cvt<<<dim3(NEXP, DIMD / 32, HDIM / 32), 256, 0, stream>>>(w1, w1t, DIMD, HDIM);
    transpose_cvt<<<dim3(NEXP, HDIM / 32, DIMD / 32), 256, 0, stream>>>(w2, w2t, HDIM, DIMD);
    gate_kernel<<<N_TOK / 4, 256, 0, stream>>>(x, gate_w, gate_b, topi, topw, counts, probsum);
    plan_kernel<<<1, 64, 0, stream>>>(counts, pbase, tiles, ntiles);
    init_rows_kernel<<<MAXROWS / 256, 256, 0, stream>>>(row_token, row_weight);
    scatter_kernel<<<(N_TOK * 2) / 256, 256, 0, stream>>>(topi, topw, pbase, cursor,
                                                          row_token, row_weight);
    gemm1_kernel<<<dim3(MAXTILES, HDIM / BN), 256, 0, stream>>>(xb, w1t, b1, hbuf,
                                                                row_token, tiles, ntiles);
    gemm2_kernel<<<dim3(MAXTILES, DIMD / BN), 256, 0, stream>>>(hbuf, w2t, b2, outp,
                                                                row_token, row_weight, tiles, ntiles);
    finalize_kernel<<<1, 64, 0, stream>>>(probsum, counts, outp + (size_t)N_TOK * DIMD);
}

// Round 2
// 409.822 us; speedup vs baseline: 1.0119x; 1.0119x over previous
//
#include <hip/hip_runtime.h>
#include <stdint.h>

#define N_TOK 8192
#define DIMD 1024
#define NEXP 8
#define HDIM 2048
#define BM 128
#define BN 128
#define BKK 64
#define MAXTILES 136            // sum ceil(c_e/128) <= 16384/128 + 8
#define MAXROWS (MAXTILES * BM) // 17408 padded row slots

typedef __attribute__((ext_vector_type(8))) short short8;
typedef __attribute__((ext_vector_type(4))) float f32x4;

__device__ __forceinline__ ushort f2bf(float f) {
    uint32_t u = __float_as_uint(f);
    u += 0x7fffu + ((u >> 16) & 1u);   // round-to-nearest-even
    return (ushort)(u >> 16);
}

// global -> LDS direct staging, 16B per lane. LDS dest must be wave-uniform.
__device__ __forceinline__ void gload_lds16(const void* gsrc, void* lds_dst) {
    __builtin_amdgcn_global_load_lds(
        (const __attribute__((address_space(1))) void*)(uintptr_t)(gsrc),
        (__attribute__((address_space(3))) void*)(uintptr_t)(lds_dst),
        16, 0, 0);
}

// ---------------- conversion kernels ----------------

__global__ void conv_x_kernel(const float* __restrict__ x, ushort* __restrict__ xb) {
    int i = blockIdx.x * blockDim.x + threadIdx.x;  // 1M threads, 8 floats each
    int base = i * 8;
    const float4* p = (const float4*)(x + base);
    float4 a = p[0], b = p[1];
    alignas(16) ushort tmp[8];
    tmp[0] = f2bf(a.x); tmp[1] = f2bf(a.y); tmp[2] = f2bf(a.z); tmp[3] = f2bf(a.w);
    tmp[4] = f2bf(b.x); tmp[5] = f2bf(b.y); tmp[6] = f2bf(b.z); tmp[7] = f2bf(b.w);
    *(short8*)(xb + base) = *(const short8*)tmp;
}

// in: [E][R][C] f32 -> out: [E][C][R] bf16  (transpose so K becomes contiguous)
__global__ void transpose_cvt(const float* __restrict__ in, ushort* __restrict__ out,
                              int R, int C) {
    __shared__ float t[32][33];
    int e = blockIdx.x, r0 = blockIdx.y * 32, c0 = blockIdx.z * 32;
    const float* pin = in + (size_t)e * R * C;
    ushort* pout = out + (size_t)e * R * C;
    int c = threadIdx.x & 31, g = threadIdx.x >> 5;  // g in 0..7
#pragma unroll
    for (int i = 0; i < 4; i++) {
        int r = g + i * 8;
        t[r][c] = pin[(size_t)(r0 + r) * C + c0 + c];
    }
    __syncthreads();
#pragma unroll
    for (int i = 0; i < 4; i++) {
        int cc = g + i * 8;
        pout[(size_t)(c0 + cc) * R + r0 + c] = f2bf(t[c][cc]);
    }
}

// ---------------- gate ----------------

__global__ void gate_kernel(const float* __restrict__ x, const float* __restrict__ gw,
                            const float* __restrict__ gb, int* __restrict__ topi,
                            float* __restrict__ topw, int* __restrict__ counts,
                            float* __restrict__ probsum) {
    __shared__ float ps[NEXP];
    __shared__ int cs[NEXP];
    int tid = threadIdx.x;
    if (tid < NEXP) { ps[tid] = 0.f; cs[tid] = 0; }
    __syncthreads();
    int wid = tid >> 6, lane = tid & 63;
    int n = blockIdx.x * 4 + wid;          // one wave per token
    const float* xr = x + (size_t)n * DIMD;
    float acc[NEXP];
#pragma unroll
    for (int e = 0; e < NEXP; e++) acc[e] = 0.f;
    for (int i = 0; i < DIMD / 64; i++) {
        int c = lane + i * 64;
        float xv = xr[c];
        const float* g = gw + (size_t)c * NEXP;
#pragma unroll
        for (int e = 0; e < NEXP; e++) acc[e] += xv * g[e];
    }
#pragma unroll
    for (int e = 0; e < NEXP; e++) {
        float v = acc[e];
#pragma unroll
        for (int off = 32; off > 0; off >>= 1) v += __shfl_xor(v, off);
        acc[e] = v + gb[e];
    }
    float m = acc[0];
#pragma unroll
    for (int e = 1; e < NEXP; e++) m = fmaxf(m, acc[e]);
    float p[NEXP], s = 0.f;
#pragma unroll
    for (int e = 0; e < NEXP; e++) { p[e] = expf(acc[e] - m); s += p[e]; }
    int e1 = 0;
#pragma unroll
    for (int e = 1; e < NEXP; e++) if (p[e] > p[e1]) e1 = e;
    int e2 = (e1 == 0) ? 1 : 0;
#pragma unroll
    for (int e = 0; e < NEXP; e++) if (e != e1 && p[e] > p[e2]) e2 = e;
    float wa = p[e1] / (p[e1] + p[e2]);
    if (lane == 0) {
        topi[n * 2] = e1; topi[n * 2 + 1] = e2;
        topw[n * 2] = wa; topw[n * 2 + 1] = 1.f - wa;
        atomicAdd(&cs[e1], 1); atomicAdd(&cs[e2], 1);
        float inv = 1.f / s;
#pragma unroll
        for (int e = 0; e < NEXP; e++) atomicAdd(&ps[e], p[e] * inv);
    }
    __syncthreads();
    if (tid < NEXP) { atomicAdd(&probsum[tid], ps[tid]); atomicAdd(&counts[tid], cs[tid]); }
}

// ---------------- routing ----------------

__global__ void plan_kernel(const int* __restrict__ counts, int* __restrict__ pbase,
                            int2* __restrict__ tiles, int* __restrict__ ntiles) {
    if (threadIdx.x != 0) return;
    int slot = 0, t = 0;
    for (int e = 0; e < NEXP; e++) {
        pbase[e] = slot;
        int nt = (counts[e] + BM - 1) / BM;
        for (int i = 0; i < nt; i++) { tiles[t] = make_int2(e, slot + i * BM); t++; }
        slot += nt * BM;
    }
    *ntiles = t;
}

__global__ void init_rows_kernel(int* __restrict__ row_token, float* __restrict__ row_weight) {
    int i = blockIdx.x * blockDim.x + threadIdx.x;
    if (i < MAXROWS) { row_token[i] = 0; row_weight[i] = 0.f; }  // padding: token0, weight0
}

__global__ void scatter_kernel(const int* __restrict__ topi, const float* __restrict__ topw,
                               const int* __restrict__ pbase, int* __restrict__ cursor,
                               int* __restrict__ row_token, float* __restrict__ row_weight) {
    __shared__ int lcnt[NEXP], lbase[NEXP];
    int t = blockIdx.x * 256 + threadIdx.x;       // pair index
    if (threadIdx.x < NEXP) lcnt[threadIdx.x] = 0;
    __syncthreads();
    int e = topi[t];
    int lpos = atomicAdd(&lcnt[e], 1);
    __syncthreads();
    if (threadIdx.x < NEXP) lbase[threadIdx.x] = atomicAdd(&cursor[threadIdx.x], lcnt[threadIdx.x]);
    __syncthreads();
    int pos = pbase[e] + lbase[e] + lpos;
    row_token[pos] = t >> 1;
    row_weight[pos] = topw[t];
}

// ---------------- grouped GEMMs ----------------
// 128x128 tile, BK=64, 4 waves (2x2), mfma_f32_16x16x32_bf16.
// 2-phase double-buffered prefetch (T3-minimum): issue next tile's
// global_load_lds BEFORE computing current tile; single barrier per K-step
// (its vmcnt(0) drain is the prefetch wait).
// LDS XOR-swizzle (byte ^= (row&7)<<4) on BOTH staging source and read.

__global__ void gemm1_kernel(const ushort* __restrict__ xb, const ushort* __restrict__ w1t,
                             const float* __restrict__ b1, ushort* __restrict__ hbuf,
                             const int* __restrict__ row_token, const int2* __restrict__ tiles,
                             const int* __restrict__ ntiles) {
    int tm = blockIdx.x;
    if (tm >= *ntiles) return;
    int e = tiles[tm].x;
    int slotbase = tiles[tm].y;
    int nbase = blockIdx.y * BN;
    __shared__ alignas(16) ushort ldsA[2][BM * BKK];
    __shared__ alignas(16) ushort ldsB[2][BN * BKK];
    int tid = threadIdx.x, lane = tid & 63, wid = tid >> 6;
    int wr = wid >> 1, wc = wid & 1;
    f32x4 acc[4][4];
#pragma unroll
    for (int i = 0; i < 4; i++)
#pragma unroll
        for (int j = 0; j < 4; j++) acc[i][j] = (f32x4){0.f, 0.f, 0.f, 0.f};
    int arow[4], acol[4], tok[4];
#pragma unroll
    for (int i = 0; i < 4; i++) {
        int p = i * 4096 + wid * 1024 + lane * 16;   // linear LDS byte offset
        int row = p >> 7;
        int srclo = (p & 127) ^ ((row & 7) << 4);    // inverse-swizzled source column
        arow[i] = row; acol[i] = srclo >> 1;
        tok[i] = row_token[slotbase + row];
    }
    const ushort* bmat = w1t + (size_t)e * HDIM * DIMD;
    const int NT = DIMD / BKK;

    // prologue: stage tile 0 into buffer 0
#pragma unroll
    for (int i = 0; i < 4; i++) {
        gload_lds16(xb + (size_t)tok[i] * DIMD + acol[i], &ldsA[0][i * 2048 + wid * 512]);
        gload_lds16(bmat + (size_t)(nbase + arow[i]) * DIMD + acol[i],
                    &ldsB[0][i * 2048 + wid * 512]);
    }
    __syncthreads();

    int cur = 0;
    for (int kt = 0; kt < NT; kt++) {
        if (kt + 1 < NT) {
            int k0 = (kt + 1) * BKK;
#pragma unroll
            for (int i = 0; i < 4; i++) {
                gload_lds16(xb + (size_t)tok[i] * DIMD + k0 + acol[i],
                            &ldsA[cur ^ 1][i * 2048 + wid * 512]);
                gload_lds16(bmat + (size_t)(nbase + arow[i]) * DIMD + k0 + acol[i],
                            &ldsB[cur ^ 1][i * 2048 + wid * 512]);
            }
        }
        const char* baseA = (const char*)&ldsA[cur][0];
        const char* baseB = (const char*)&ldsB[cur][0];
#pragma unroll
        for (int kk = 0; kk < 2; kk++) {
            short8 af[4], bfv[4];
#pragma unroll
            for (int im = 0; im < 4; im++) {
                int row = wr * 64 + im * 16 + (lane & 15);
                int kbyte = kk * 64 + ((lane >> 4) * 16);
                int off = row * 128 + (kbyte ^ ((row & 7) << 4));
                af[im] = *(const short8*)(baseA + off);
            }
#pragma unroll
            for (int in = 0; in < 4; in++) {
                int row = wc * 64 + in * 16 + (lane & 15);
                int kbyte = kk * 64 + ((lane >> 4) * 16);
                int off = row * 128 + (kbyte ^ ((row & 7) << 4));
                bfv[in] = *(const short8*)(baseB + off);
            }
#pragma unroll
            for (int im = 0; im < 4; im++)
#pragma unroll
                for (int in = 0; in < 4; in++)
                    acc[im][in] = __builtin_amdgcn_mfma_f32_16x16x32_bf16(af[im], bfv[in],
                                                                          acc[im][in], 0, 0, 0);
        }
        __syncthreads();   // drains vmcnt(0): next buffer ready; syncs readers
        cur ^= 1;
    }
    const float* b1e = b1 + (size_t)e * HDIM;
#pragma unroll
    for (int im = 0; im < 4; im++) {
#pragma unroll
        for (int in = 0; in < 4; in++) {
            int col = nbase + wc * 64 + in * 16 + (lane & 15);
            float bias = b1e[col];
#pragma unroll
            for (int r = 0; r < 4; r++) {
                int row = slotbase + wr * 64 + im * 16 + (lane >> 4) * 4 + r;
                float v = fmaxf(acc[im][in][r] + bias, 0.f);
                hbuf[(size_t)row * HDIM + col] = f2bf(v);
            }
        }
    }
}

__global__ void gemm2_kernel(const ushort* __restrict__ hbuf, const ushort* __restrict__ w2t,
                             const float* __restrict__ b2, float* __restrict__ outp,
                             const int* __restrict__ row_token, const float* __restrict__ row_weight,
                             const int2* __restrict__ tiles, const int* __restrict__ ntiles) {
    int tm = blockIdx.x;
    if (tm >= *ntiles) return;
    int e = tiles[tm].x;
    int slotbase = tiles[tm].y;
    int nbase = blockIdx.y * BN;
    __shared__ alignas(16) ushort ldsA[2][BM * BKK];
    __shared__ alignas(16) ushort ldsB[2][BN * BKK];
    int tid = threadIdx.x, lane = tid & 63, wid = tid >> 6;
    int wr = wid >> 1, wc = wid & 1;
    f32x4 acc[4][4];
#pragma unroll
    for (int i = 0; i < 4; i++)
#pragma unroll
        for (int j = 0; j < 4; j++) acc[i][j] = (f32x4){0.f, 0.f, 0.f, 0.f};
    int arow[4], acol[4];
#pragma unroll
    for (int i = 0; i < 4; i++) {
        int p = i * 4096 + wid * 1024 + lane * 16;
        int row = p >> 7;
        int srclo = (p & 127) ^ ((row & 7) << 4);
        arow[i] = row; acol[i] = srclo >> 1;
    }
    const ushort* amat = hbuf + (size_t)slotbase * HDIM;
    const ushort* bmat = w2t + (size_t)e * DIMD * HDIM;
    const int NT = HDIM / BKK;

#pragma unroll
    for (int i = 0; i < 4; i++) {
        gload_lds16(amat + (size_t)arow[i] * HDIM + acol[i], &ldsA[0][i * 2048 + wid * 512]);
        gload_lds16(bmat + (size_t)(nbase + arow[i]) * HDIM + acol[i],
                    &ldsB[0][i * 2048 + wid * 512]);
    }
    __syncthreads();

    int cur = 0;
    for (int kt = 0; kt < NT; kt++) {
        if (kt + 1 < NT) {
            int k0 = (kt + 1) * BKK;
#pragma unroll
            for (int i = 0; i < 4; i++) {
                gload_lds16(amat + (size_t)arow[i] * HDIM + k0 + acol[i],
                            &ldsA[cur ^ 1][i * 2048 + wid * 512]);
                gload_lds16(bmat + (size_t)(nbase + arow[i]) * HDIM + k0 + acol[i],
                            &ldsB[cur ^ 1][i * 2048 + wid * 512]);
            }
        }
        const char* baseA = (const char*)&ldsA[cur][0];
        const char* baseB = (const char*)&ldsB[cur][0];
#pragma unroll
        for (int kk = 0; kk < 2; kk++) {
            short8 af[4], bfv[4];
#pragma unroll
            for (int im = 0; im < 4; im++) {
                int row = wr * 64 + im * 16 + (lane & 15);
                int kbyte = kk * 64 + ((lane >> 4) * 16);
                int off = row * 128 + (kbyte ^ ((row & 7) << 4));
                af[im] = *(const short8*)(baseA + off);
            }
#pragma unroll
            for (int in = 0; in < 4; in++) {
                int row = wc * 64 + in * 16 + (lane & 15);
                int kbyte = kk * 64 + ((lane >> 4) * 16);
                int off = row * 128 + (kbyte ^ ((row & 7) << 4));
                bfv[in] = *(const short8*)(baseB + off);
            }
#pragma unroll
            for (int im = 0; im < 4; im++)
#pragma unroll
                for (int in = 0; in < 4; in++)
                    acc[im][in] = __builtin_amdgcn_mfma_f32_16x16x32_bf16(af[im], bfv[in],
                                                                          acc[im][in], 0, 0, 0);
        }
        __syncthreads();
        cur ^= 1;
    }
    const float* b2e = b2 + (size_t)e * DIMD;
#pragma unroll
    for (int im = 0; im < 4; im++) {
#pragma unroll
        for (int r = 0; r < 4; r++) {
            int srow = slotbase + wr * 64 + im * 16 + (lane >> 4) * 4 + r;
            int token = row_token[srow];
            float w = row_weight[srow];
            float* orow = outp + (size_t)token * DIMD;
#pragma unroll
            for (int in = 0; in < 4; in++) {
                int col = nbase + wc * 64 + in * 16 + (lane & 15);
                float v = acc[im][in][r] + b2e[col];
                atomicAdd(&orow[col], w * v);
            }
        }
    }
}

__global__ void finalize_kernel(const float* __restrict__ probsum, const int* __restrict__ counts,
                                float* __restrict__ loss_out) {
    if (threadIdx.x == 0) {
        float l = 0.f;
        for (int e = 0; e < NEXP; e++) l += probsum[e] * (float)counts[e];
        *loss_out = l / ((float)N_TOK * (float)N_TOK);
    }
}

// ---------------- launch ----------------

extern "C" void kernel_launch(void* const* d_in, const int* in_sizes, int n_in,
                              void* d_out, int out_size, void* d_ws, size_t ws_size,
                              hipStream_t stream) {
    const float* x      = (const float*)d_in[0];
    const float* gate_w = (const float*)d_in[1];
    const float* gate_b = (const float*)d_in[2];
    const float* w1     = (const float*)d_in[3];
    const float* b1     = (const float*)d_in[4];
    const float* w2     = (const float*)d_in[5];
    const float* b2     = (const float*)d_in[6];
    float* outp = (float*)d_out;

    char* ws = (char*)d_ws;
    ushort* xb   = (ushort*)(ws);                 // 16 MB
    ushort* w1t  = (ushort*)(ws + 16777216);      // 32 MB  [E][H][D] bf16
    ushort* w2t  = (ushort*)(ws + 50331648);      // 32 MB  [E][D][H] bf16
    ushort* hbuf = (ushort*)(ws + 83886080);      // 68 MB  [MAXROWS][H] bf16
    char* ctrl   = ws + 155189248;
    int*   counts     = (int*)(ctrl + 0);
    int*   cursor     = (int*)(ctrl + 32);
    float* probsum    = (float*)(ctrl + 64);
    int*   ntiles     = (int*)(ctrl + 96);
    int*   pbase      = (int*)(ctrl + 128);
    int2*  tiles      = (int2*)(ctrl + 160);
    int*   topi       = (int*)(ctrl + 2048);
    float* topw       = (float*)(ctrl + 2048 + 65536);
    int*   row_token  = (int*)(ctrl + 2048 + 131072);
    float* row_weight = (float*)(ctrl + 2048 + 131072 + 69632);

    hipMemsetAsync(ctrl, 0, 128, stream);                                  // counts/cursor/probsum/ntiles
    hipMemsetAsync(d_out, 0, (size_t)out_size * sizeof(float), stream);    // final accumulated via atomics

    conv_x_kernel<<<4096, 256, 0, stream>>>(x, xb);
    transpose_cvt<<<dim3(NEXP, DIMD / 32, HDIM / 32), 256, 0, stream>>>(w1, w1t, DIMD, HDIM);
    transpose_cvt<<<dim3(NEXP, HDIM / 32, DIMD / 32), 256, 0, stream>>>(w2, w2t, HDIM, DIMD);
    gate_kernel<<<N_TOK / 4, 256, 0, stream>>>(x, gate_w, gate_b, topi, topw, counts, probsum);
    plan_kernel<<<1, 64, 0, stream>>>(counts, pbase, tiles, ntiles);
    init_rows_kernel<<<MAXROWS / 256, 256, 0, stream>>>(row_token, row_weight);
    scatter_kernel<<<(N_TOK * 2) / 256, 256, 0, stream>>>(topi, topw, pbase, cursor,
                                                          row_token, row_weight);
    gemm1_kernel<<<dim3(MAXTILES, HDIM / BN), 256, 0, stream>>>(xb, w1t, b1, hbuf,
                                                                row_token, tiles, ntiles);
    gemm2_kernel<<<dim3(MAXTILES, DIMD / BN), 256, 0, stream>>>(hbuf, w2t, b2, outp,
                                                                row_token, row_weight, tiles, ntiles);
    finalize_kernel<<<1, 64, 0, stream>>>(probsum, counts, outp + (size_t)N_TOK * DIMD);
}